// Round 8
// baseline (243.315 us; speedup 1.0000x reference)
//
#include <hip/hip_runtime.h>

typedef __bf16 bf16_t;
typedef bf16_t bf16x8 __attribute__((ext_vector_type(8)));
typedef bf16_t bf16x4 __attribute__((ext_vector_type(4)));
typedef float f32x4 __attribute__((ext_vector_type(4)));

__device__ __forceinline__ f32x4 mfma16(bf16x8 a, bf16x8 b, f32x4 c) {
  return __builtin_amdgcn_mfma_f32_16x16x32_bf16(a, b, c, 0, 0, 0);
}

__device__ __forceinline__ void gload16(const bf16_t* g, bf16_t* l) {
  __builtin_amdgcn_global_load_lds(
      (const __attribute__((address_space(1))) void*)g,
      (__attribute__((address_space(3))) void*)l, 16, 0, 0);
}

// ------- merged prep: x f32->bf16 convert + both weight transposes -------
__global__ void prep_kernel(const float* __restrict__ x, const float* __restrict__ wq,
                            const float* __restrict__ wp, bf16_t* __restrict__ xb,
                            bf16_t* __restrict__ wqt, bf16_t* __restrict__ wpt) {
  __shared__ bf16_t tile[32][33];
  const int bid = blockIdx.x;
  if (bid < 12288) {
    int i = bid * 256 + threadIdx.x;
    float4 v = ((const float4*)x)[i];
    bf16x4 o;
    o[0] = (bf16_t)v.x; o[1] = (bf16_t)v.y; o[2] = (bf16_t)v.z; o[3] = (bf16_t)v.w;
    *(bf16x4*)&xb[(size_t)i * 4] = o;
    return;
  }
  const int t = bid - 12288;
  const int ty = t / 96, txb = t % 96;
  const float* in;
  bf16_t* out;
  int N, n0;
  if (txb < 72) { in = wq; out = wqt; N = 2304; n0 = txb * 32; }
  else          { in = wp; out = wpt; N = 768;  n0 = (txb - 72) * 32; }
  const int k0 = ty * 32;
  const int tx = threadIdx.x & 31, tyy = threadIdx.x >> 5;
#pragma unroll
  for (int ph = 0; ph < 4; ++ph) {
    int k = tyy + ph * 8;
    tile[k][tx] = (bf16_t)in[(size_t)(k0 + k) * N + n0 + tx];
  }
  __syncthreads();
#pragma unroll
  for (int ph = 0; ph < 4; ++ph) {
    int n = tyy + ph * 8;
    out[(size_t)(n0 + n) * 768 + k0 + tx] = tile[tx][n];
  }
}

// ------- persistent 128x128 bf16 GEMM, A via LDS, B direct global(L2)->regs -------
// C = A[M][768] * Bt[N][768]^T. BK=64, 4 waves (2x2). LDS = A dbuf only (32 KiB)
// -> 3 blocks/CU. B-fragments load straight to named reg sets BA/BB (kt unrolled
// x2, compile-time indexed). Round-3 staging/swizzle/sync for A.
template <int NBN, int JPB, bool F32OUT>
__global__ __launch_bounds__(256, 3) void gemm_bl(
    const bf16_t* __restrict__ A, const bf16_t* __restrict__ Bt,
    void* __restrict__ Cout, int N) {
  constexpr int K = 768;
  constexpr int NKT = 12;  // K/64
  __shared__ bf16_t As[2][128 * 64];
  const int tid = threadIdx.x;
  const int lane = tid & 63;
  const int w = tid >> 6;
  const int wm = w >> 1, wn = w & 1;
  const int lr = lane & 15, kg = lane >> 4;

  // XCD-chunked remap: each XCD gets a contiguous job window (B panels L2-hot)
  const int G = gridDim.x;
  const int bid = blockIdx.x;
  const int lb = (bid & 7) * (G >> 3) + (bid >> 3);
  const int start = lb * JPB;
  const int bm = start / NBN;  // constant per block (JPB divides NBN)
  const int bn0 = start - bm * NBN;
  const bf16_t* Aj = A + (size_t)bm * (128 * K);

  const int sr = tid >> 3, sslot = tid & 7;
  auto stageA = [&](int buf, int k0) {
#pragma unroll
    for (int it = 0; it < 4; ++it) {
      int rr = it * 32 + sr;
      gload16(Aj + (size_t)rr * K + (k0 + ((sslot ^ (rr & 7)) << 3)),
              &As[buf][(it * 256 + tid) * 8]);
    }
  };

  // B fragment row bases (per nq), fixed per job
  auto loadB = [&](bf16x8 (&dst)[4][2], int bn, int kt) {
    const size_t rb = (size_t)(bn * 128 + wn * 64 + lr) * K + (kt << 6) + kg * 8;
#pragma unroll
    for (int nq = 0; nq < 4; ++nq)
#pragma unroll
      for (int kk = 0; kk < 2; ++kk)
        dst[nq][kk] = *(const bf16x8*)&Bt[rb + (size_t)nq * (16 * K) + kk * 32];
  };

  f32x4 acc[4][4];
  bf16x8 BA[4][2], BB[4][2];

  auto compute = [&](int buf, bf16x8 (&B)[4][2]) {
#pragma unroll
    for (int kk = 0; kk < 2; ++kk) {
      const int slot = ((kk << 2) + kg) ^ (lr & 7);
      bf16x8 af[4];
#pragma unroll
      for (int mq = 0; mq < 4; ++mq) {
        int rr = wm * 64 + mq * 16 + lr;
        af[mq] = *(const bf16x8*)&As[buf][(rr << 6) + (slot << 3)];
      }
#pragma unroll
      for (int mq = 0; mq < 4; ++mq)
#pragma unroll
        for (int nq = 0; nq < 4; ++nq)
          acc[mq][nq] = mfma16(af[mq], B[nq][kk], acc[mq][nq]);
    }
  };

  // prologue
  stageA(0, 0);
  loadB(BA, bn0, 0);
  __syncthreads();
  int buf = 0;

  for (int j = 0; j < JPB; ++j) {
    const int bn = bn0 + j;
#pragma unroll
    for (int i = 0; i < 4; ++i)
#pragma unroll
      for (int n = 0; n < 4; ++n) acc[i][n] = (f32x4){0.f, 0.f, 0.f, 0.f};

    for (int kt2 = 0; kt2 < NKT / 2; ++kt2) {
      const int kt = kt2 * 2;
      // even step: compute(kt) with BA; prefetch kt+1
      stageA(buf ^ 1, (kt + 1) << 6);
      loadB(BB, bn, kt + 1);
      compute(buf, BA);
      __syncthreads();
      buf ^= 1;
      // odd step: compute(kt+1) with BB; prefetch kt+2 (or next job kt=0)
      const bool injob = (kt + 2 < NKT);
      const bool haveNext = injob || (j + 1 < JPB);
      if (haveNext) {
        const int nk = injob ? kt + 2 : 0;
        stageA(buf ^ 1, nk << 6);
        loadB(BA, injob ? bn : bn + 1, nk);
      }
      compute(buf, BB);
      __syncthreads();
      buf ^= 1;
    }

    const int row0 = bm * 128 + wm * 64 + kg * 4;
    const int col0 = bn * 128 + wn * 64 + lr;
#pragma unroll
    for (int mq = 0; mq < 4; ++mq)
#pragma unroll
      for (int nq = 0; nq < 4; ++nq)
#pragma unroll
        for (int rr = 0; rr < 4; ++rr) {
          size_t idx = (size_t)(row0 + mq * 16 + rr) * N + (col0 + nq * 16);
          if constexpr (F32OUT)
            ((float*)Cout)[idx] = acc[mq][nq][rr];
          else
            ((bf16_t*)Cout)[idx] = (bf16_t)acc[mq][nq][rr];
        }
  }
}

// ---------------- causal attention: one block per (b,h) ----------------
#define ATT_H 12
__global__ __launch_bounds__(256, 2) void attn_kernel(const bf16_t* __restrict__ qkv,
                                                      bf16_t* __restrict__ obuf) {
  __shared__ bf16_t Ks[128 * 72];
  __shared__ bf16_t Vt[64 * 136];
  __shared__ bf16_t Ps[128 * 136];
  const int tid = threadIdx.x, lane = tid & 63, w = tid >> 6;
  const int lr = lane & 15, kg = lane >> 4;
  const int bh = blockIdx.x;
  const int b = bh / ATT_H, h = bh % ATT_H;
  const size_t base = (size_t)b * 128 * 2304;
  const int hoff = h * 64;

#pragma unroll
  for (int it = 0; it < 4; ++it) {
    int idx = it * 256 + tid;
    int r = idx >> 3, slot = idx & 7;
    bf16x8 v = *(const bf16x8*)&qkv[base + (size_t)r * 2304 + 768 + hoff + slot * 8];
    *(bf16x8*)&Ks[r * 72 + slot * 8] = v;
  }
#pragma unroll 4
  for (int it = 0; it < 32; ++it) {
    int idx = it * 256 + tid;
    int t = idx >> 6, d = idx & 63;
    Vt[d * 136 + t] = qkv[base + (size_t)t * 2304 + 1536 + hoff + d];
  }
  const int qrow0 = w * 32;
  bf16x8 qf[2][2];
#pragma unroll
  for (int mt = 0; mt < 2; ++mt)
#pragma unroll
    for (int kk = 0; kk < 2; ++kk)
      qf[mt][kk] = *(const bf16x8*)&qkv[base + (size_t)(qrow0 + mt * 16 + lr) * 2304 + hoff +
                                        kk * 32 + kg * 8];
  __syncthreads();

  const int NT = 2 * w + 2;
  f32x4 acc[2][8];
#pragma unroll
  for (int mt = 0; mt < 2; ++mt)
#pragma unroll
    for (int nt = 0; nt < 8; ++nt) acc[mt][nt] = (f32x4){0.f, 0.f, 0.f, 0.f};

#pragma unroll
  for (int nt = 0; nt < 8; ++nt) {
    if (nt < NT) {
#pragma unroll
      for (int kk = 0; kk < 2; ++kk) {
        bf16x8 kf = *(const bf16x8*)&Ks[(nt * 16 + lr) * 72 + kk * 32 + kg * 8];
        acc[0][nt] = mfma16(qf[0][kk], kf, acc[0][nt]);
        acc[1][nt] = mfma16(qf[1][kk], kf, acc[1][nt]);
      }
    }
  }

#pragma unroll
  for (int mt = 0; mt < 2; ++mt) {
#pragma unroll
    for (int rr = 0; rr < 4; ++rr) {
      const int row = qrow0 + mt * 16 + kg * 4 + rr;
      float m = -1e30f;
#pragma unroll
      for (int nt = 0; nt < 8; ++nt) {
        if (nt < NT) {
          int col = nt * 16 + lr;
          float sv = acc[mt][nt][rr] * 0.125f;
          sv = (col <= row) ? sv : -1e30f;
          acc[mt][nt][rr] = sv;
          m = fmaxf(m, sv);
        }
      }
      m = fmaxf(m, __shfl_xor(m, 1));
      m = fmaxf(m, __shfl_xor(m, 2));
      m = fmaxf(m, __shfl_xor(m, 4));
      m = fmaxf(m, __shfl_xor(m, 8));
      float ssum = 0.f;
#pragma unroll
      for (int nt = 0; nt < 8; ++nt) {
        if (nt < NT) {
          float p = __builtin_amdgcn_exp2f((acc[mt][nt][rr] - m) * 1.44269504f);
          acc[mt][nt][rr] = p;
          ssum += p;
        }
      }
      ssum += __shfl_xor(ssum, 1);
      ssum += __shfl_xor(ssum, 2);
      ssum += __shfl_xor(ssum, 4);
      ssum += __shfl_xor(ssum, 8);
      float inv = 1.0f / ssum;
#pragma unroll
      for (int nt = 0; nt < 8; ++nt) {
        if (nt < NT) Ps[row * 136 + nt * 16 + lr] = (bf16_t)(acc[mt][nt][rr] * inv);
      }
    }
  }

  f32x4 oacc[2][4];
#pragma unroll
  for (int mt = 0; mt < 2; ++mt)
#pragma unroll
    for (int dt = 0; dt < 4; ++dt) oacc[mt][dt] = (f32x4){0.f, 0.f, 0.f, 0.f};

  const int KS = w + 1;
#pragma unroll
  for (int ks = 0; ks < 4; ++ks) {
    if (ks < KS) {
      bf16x8 pa0 = *(const bf16x8*)&Ps[(qrow0 + lr) * 136 + ks * 32 + kg * 8];
      bf16x8 pa1 = *(const bf16x8*)&Ps[(qrow0 + 16 + lr) * 136 + ks * 32 + kg * 8];
#pragma unroll
      for (int dt = 0; dt < 4; ++dt) {
        bf16x8 vb = *(const bf16x8*)&Vt[(dt * 16 + lr) * 136 + ks * 32 + kg * 8];
        oacc[0][dt] = mfma16(pa0, vb, oacc[0][dt]);
        oacc[1][dt] = mfma16(pa1, vb, oacc[1][dt]);
      }
    }
  }

#pragma unroll
  for (int mt = 0; mt < 2; ++mt)
#pragma unroll
    for (int dt = 0; dt < 4; ++dt)
#pragma unroll
      for (int rr = 0; rr < 4; ++rr) {
        int t = qrow0 + mt * 16 + kg * 4 + rr;
        obuf[((size_t)b * 128 + t) * 768 + hoff + dt * 16 + lr] = (bf16_t)oacc[mt][dt][rr];
      }
}

// ---------------- launch ----------------
extern "C" void kernel_launch(void* const* d_in, const int* in_sizes, int n_in,
                              void* d_out, int out_size, void* d_ws, size_t ws_size,
                              hipStream_t stream) {
  const float* x = (const float*)d_in[0];       // [128,128,768]
  const float* w_qkv = (const float*)d_in[1];   // [768,2304]
  const float* w_proj = (const float*)d_in[2];  // [768,768]
  float* out = (float*)d_out;
  char* ws = (char*)d_ws;

  bf16_t* xb     = (bf16_t*)(ws);              // 16384*768*2   = 25,165,824
  bf16_t* wqkvt  = (bf16_t*)(ws + 25165824);   // 2304*768*2    =  3,538,944
  bf16_t* wprojt = (bf16_t*)(ws + 28704768);   // 768*768*2     =  1,179,648
  bf16_t* qkv    = (bf16_t*)(ws + 29884416);   // 16384*2304*2  = 75,497,472
  bf16_t* obuf   = (bf16_t*)(ws + 105381888);  // 16384*768*2   = 25,165,824

  prep_kernel<<<dim3(12288 + 2304), dim3(256), 0, stream>>>(x, w_qkv, w_proj, xb, wqkvt, wprojt);
  // GEMM1: jobs = 128 bm x 18 bn = 2304 = 768 blocks x 3 (same bm per block)
  gemm_bl<18, 3, false><<<dim3(768), dim3(256), 0, stream>>>(xb, wqkvt, (void*)qkv, 2304);
  attn_kernel<<<dim3(1536), dim3(256), 0, stream>>>(qkv, obuf);
  // GEMM2: jobs = 128 bm x 6 bn = 768 blocks x 1; 3 blocks/CU = 1 round
  gemm_bl<6, 1, true><<<dim3(768), dim3(256), 0, stream>>>(obuf, wprojt, (void*)out, 768);
}

// Round 9
// 163.894 us; speedup vs baseline: 1.4846x; 1.4846x over previous
//
#include <hip/hip_runtime.h>

typedef __bf16 bf16_t;
typedef bf16_t bf16x8 __attribute__((ext_vector_type(8)));
typedef bf16_t bf16x4 __attribute__((ext_vector_type(4)));
typedef float f32x4 __attribute__((ext_vector_type(4)));

__device__ __forceinline__ f32x4 mfma16(bf16x8 a, bf16x8 b, f32x4 c) {
  return __builtin_amdgcn_mfma_f32_16x16x32_bf16(a, b, c, 0, 0, 0);
}

__device__ __forceinline__ void gload16(const bf16_t* g, bf16_t* l) {
  __builtin_amdgcn_global_load_lds(
      (const __attribute__((address_space(1))) void*)g,
      (__attribute__((address_space(3))) void*)l, 16, 0, 0);
}

// ------- prep: x f32->bf16 convert + weight fragment-packing -------
// Packed B layout: Bp[((T*24 + KB)*64 + lane)*8 + j] = w[KB*32+(lane>>4)*8+j][T*16+(lane&15)]
// (T = 16-wide n-tile, KB = 32-deep k-block) -> a wave's (nq,kk) fragment is
// one contiguous 1KB block; loadB is 16B/lane fully coalesced.
__global__ void prep_kernel(const float* __restrict__ x, const float* __restrict__ wq,
                            const float* __restrict__ wp, bf16_t* __restrict__ xb,
                            bf16_t* __restrict__ wqt, bf16_t* __restrict__ wpt) {
  const int bid = blockIdx.x;
  if (bid < 12288) {
    int i = bid * 256 + threadIdx.x;
    float4 v = ((const float4*)x)[i];
    bf16x4 o;
    o[0] = (bf16_t)v.x; o[1] = (bf16_t)v.y; o[2] = (bf16_t)v.z; o[3] = (bf16_t)v.w;
    *(bf16x4*)&xb[(size_t)i * 4] = o;
    return;
  }
  int u = (bid - 12288) * 4 + (threadIdx.x >> 6);
  const float* in;
  bf16_t* outp;
  int N2;
  if (u < 3456) { in = wq; outp = wqt; N2 = 2304; }
  else          { u -= 3456; in = wp; outp = wpt; N2 = 768; }
  const int T = u / 24, KB = u % 24;
  const int lane = threadIdx.x & 63;
  const int k0 = KB * 32 + (lane >> 4) * 8;
  const int n = T * 16 + (lane & 15);
  bf16x8 o;
#pragma unroll
  for (int j = 0; j < 8; ++j) o[j] = (bf16_t)in[(size_t)(k0 + j) * N2 + n];
  *(bf16x8*)&outp[(size_t)(T * 24 + KB) * 512 + lane * 8] = o;
}

// ------- persistent 128x128 bf16 GEMM: A via LDS (round-3 path), B packed->regs -------
// BK=64, 4 waves (2x2). LDS = A dbuf only, 32 KiB -> 3 blocks/CU. B fragments are
// coalesced 16B/lane loads from the fragment-packed buffer (L2-hot), double-buffered
// in named reg sets BA/BB (kt unrolled x2). Sync = round-3 proven pattern.
template <int NBN, int JPB, bool F32OUT>
__global__ __launch_bounds__(256, 3) void gemm_pk(
    const bf16_t* __restrict__ A, const bf16_t* __restrict__ Bp,
    void* __restrict__ Cout, int N) {
  constexpr int K = 768;
  constexpr int NKT = 12;  // K/64
  constexpr int NKB = 24;  // K/32 packed k-blocks
  __shared__ bf16_t As[2][128 * 64];
  const int tid = threadIdx.x;
  const int lane = tid & 63;
  const int w = tid >> 6;
  const int wm = w >> 1, wn = w & 1;
  const int lr = lane & 15, kg = lane >> 4;

  // XCD-chunked remap: each XCD gets a contiguous job window (B panels L2-hot)
  const int G = gridDim.x;
  const int bid = blockIdx.x;
  const int lb = (bid & 7) * (G >> 3) + (bid >> 3);
  const int start = lb * JPB;
  const int bm = start / NBN;  // constant per block (JPB*k pattern keeps same bm)
  const int bn0 = start - bm * NBN;
  const bf16_t* Aj = A + (size_t)bm * (128 * K);

  const int sr = tid >> 3, sslot = tid & 7;
  auto stageA = [&](int buf, int k0) {
#pragma unroll
    for (int it = 0; it < 4; ++it) {
      int rr = it * 32 + sr;
      gload16(Aj + (size_t)rr * K + (k0 + ((sslot ^ (rr & 7)) << 3)),
              &As[buf][(it * 256 + tid) * 8]);
    }
  };

  // coalesced fragment loads: 8 x 16B/lane per K-step
  auto loadB = [&](bf16x8 (&dst)[4][2], int bn, int kt) {
    const bf16_t* base = Bp + ((size_t)(bn * 8 + wn * 4) * NKB + kt * 2) * 512 + lane * 8;
#pragma unroll
    for (int nq = 0; nq < 4; ++nq)
#pragma unroll
      for (int kk = 0; kk < 2; ++kk)
        dst[nq][kk] = *(const bf16x8*)&base[(nq * NKB + kk) * 512];
  };

  f32x4 acc[4][4];
  bf16x8 BA[4][2], BB[4][2];

  auto compute = [&](int buf, bf16x8 (&B)[4][2]) {
#pragma unroll
    for (int kk = 0; kk < 2; ++kk) {
      const int slot = ((kk << 2) + kg) ^ (lr & 7);
      bf16x8 af[4];
#pragma unroll
      for (int mq = 0; mq < 4; ++mq) {
        int rr = wm * 64 + mq * 16 + lr;
        af[mq] = *(const bf16x8*)&As[buf][(rr << 6) + (slot << 3)];
      }
#pragma unroll
      for (int mq = 0; mq < 4; ++mq)
#pragma unroll
        for (int nq = 0; nq < 4; ++nq)
          acc[mq][nq] = mfma16(af[mq], B[nq][kk], acc[mq][nq]);
    }
  };

  // prologue
  stageA(0, 0);
  loadB(BA, bn0, 0);
  __syncthreads();
  int buf = 0;

  for (int j = 0; j < JPB; ++j) {
    const int bn = bn0 + j;
#pragma unroll
    for (int i = 0; i < 4; ++i)
#pragma unroll
      for (int n = 0; n < 4; ++n) acc[i][n] = (f32x4){0.f, 0.f, 0.f, 0.f};

    for (int kt2 = 0; kt2 < NKT / 2; ++kt2) {
      const int kt = kt2 * 2;
      // even step: compute(kt) w/ BA; prefetch kt+1 (A->LDS, B->BB)
      stageA(buf ^ 1, (kt + 1) << 6);
      loadB(BB, bn, kt + 1);
      compute(buf, BA);
      __syncthreads();
      buf ^= 1;
      // odd step: compute(kt+1) w/ BB; prefetch kt+2 (or next job kt=0) into BA
      const bool injob = (kt + 2 < NKT);
      const bool haveNext = injob || (j + 1 < JPB);
      if (haveNext) {
        const int nk = injob ? kt + 2 : 0;
        stageA(buf ^ 1, nk << 6);
        loadB(BA, injob ? bn : bn + 1, nk);
      }
      compute(buf, BB);
      __syncthreads();
      buf ^= 1;
    }

    const int row0 = bm * 128 + wm * 64 + kg * 4;
    const int col0 = bn * 128 + wn * 64 + lr;
#pragma unroll
    for (int mq = 0; mq < 4; ++mq)
#pragma unroll
      for (int nq = 0; nq < 4; ++nq)
#pragma unroll
        for (int rr = 0; rr < 4; ++rr) {
          size_t idx = (size_t)(row0 + mq * 16 + rr) * N + (col0 + nq * 16);
          if constexpr (F32OUT)
            ((float*)Cout)[idx] = acc[mq][nq][rr];
          else
            ((bf16_t*)Cout)[idx] = (bf16_t)acc[mq][nq][rr];
        }
  }
}

// ---------------- causal attention: one block per (b,h) ----------------
#define ATT_H 12
__global__ __launch_bounds__(256, 2) void attn_kernel(const bf16_t* __restrict__ qkv,
                                                      bf16_t* __restrict__ obuf) {
  __shared__ bf16_t Ks[128 * 72];
  __shared__ bf16_t Vt[64 * 136];
  __shared__ bf16_t Ps[128 * 136];
  const int tid = threadIdx.x, lane = tid & 63, w = tid >> 6;
  const int lr = lane & 15, kg = lane >> 4;
  const int bh = blockIdx.x;
  const int b = bh / ATT_H, h = bh % ATT_H;
  const size_t base = (size_t)b * 128 * 2304;
  const int hoff = h * 64;

#pragma unroll
  for (int it = 0; it < 4; ++it) {
    int idx = it * 256 + tid;
    int r = idx >> 3, slot = idx & 7;
    bf16x8 v = *(const bf16x8*)&qkv[base + (size_t)r * 2304 + 768 + hoff + slot * 8];
    *(bf16x8*)&Ks[r * 72 + slot * 8] = v;
  }
#pragma unroll 4
  for (int it = 0; it < 32; ++it) {
    int idx = it * 256 + tid;
    int t = idx >> 6, d = idx & 63;
    Vt[d * 136 + t] = qkv[base + (size_t)t * 2304 + 1536 + hoff + d];
  }
  const int qrow0 = w * 32;
  bf16x8 qf[2][2];
#pragma unroll
  for (int mt = 0; mt < 2; ++mt)
#pragma unroll
    for (int kk = 0; kk < 2; ++kk)
      qf[mt][kk] = *(const bf16x8*)&qkv[base + (size_t)(qrow0 + mt * 16 + lr) * 2304 + hoff +
                                        kk * 32 + kg * 8];
  __syncthreads();

  const int NT = 2 * w + 2;
  f32x4 acc[2][8];
#pragma unroll
  for (int mt = 0; mt < 2; ++mt)
#pragma unroll
    for (int nt = 0; nt < 8; ++nt) acc[mt][nt] = (f32x4){0.f, 0.f, 0.f, 0.f};

#pragma unroll
  for (int nt = 0; nt < 8; ++nt) {
    if (nt < NT) {
#pragma unroll
      for (int kk = 0; kk < 2; ++kk) {
        bf16x8 kf = *(const bf16x8*)&Ks[(nt * 16 + lr) * 72 + kk * 32 + kg * 8];
        acc[0][nt] = mfma16(qf[0][kk], kf, acc[0][nt]);
        acc[1][nt] = mfma16(qf[1][kk], kf, acc[1][nt]);
      }
    }
  }

#pragma unroll
  for (int mt = 0; mt < 2; ++mt) {
#pragma unroll
    for (int rr = 0; rr < 4; ++rr) {
      const int row = qrow0 + mt * 16 + kg * 4 + rr;
      float m = -1e30f;
#pragma unroll
      for (int nt = 0; nt < 8; ++nt) {
        if (nt < NT) {
          int col = nt * 16 + lr;
          float sv = acc[mt][nt][rr] * 0.125f;
          sv = (col <= row) ? sv : -1e30f;
          acc[mt][nt][rr] = sv;
          m = fmaxf(m, sv);
        }
      }
      m = fmaxf(m, __shfl_xor(m, 1));
      m = fmaxf(m, __shfl_xor(m, 2));
      m = fmaxf(m, __shfl_xor(m, 4));
      m = fmaxf(m, __shfl_xor(m, 8));
      float ssum = 0.f;
#pragma unroll
      for (int nt = 0; nt < 8; ++nt) {
        if (nt < NT) {
          float p = __builtin_amdgcn_exp2f((acc[mt][nt][rr] - m) * 1.44269504f);
          acc[mt][nt][rr] = p;
          ssum += p;
        }
      }
      ssum += __shfl_xor(ssum, 1);
      ssum += __shfl_xor(ssum, 2);
      ssum += __shfl_xor(ssum, 4);
      ssum += __shfl_xor(ssum, 8);
      float inv = 1.0f / ssum;
#pragma unroll
      for (int nt = 0; nt < 8; ++nt) {
        if (nt < NT) Ps[row * 136 + nt * 16 + lr] = (bf16_t)(acc[mt][nt][rr] * inv);
      }
    }
  }

  f32x4 oacc[2][4];
#pragma unroll
  for (int mt = 0; mt < 2; ++mt)
#pragma unroll
    for (int dt = 0; dt < 4; ++dt) oacc[mt][dt] = (f32x4){0.f, 0.f, 0.f, 0.f};

  const int KS = w + 1;
#pragma unroll
  for (int ks = 0; ks < 4; ++ks) {
    if (ks < KS) {
      bf16x8 pa0 = *(const bf16x8*)&Ps[(qrow0 + lr) * 136 + ks * 32 + kg * 8];
      bf16x8 pa1 = *(const bf16x8*)&Ps[(qrow0 + 16 + lr) * 136 + ks * 32 + kg * 8];
#pragma unroll
      for (int dt = 0; dt < 4; ++dt) {
        bf16x8 vb = *(const bf16x8*)&Vt[(dt * 16 + lr) * 136 + ks * 32 + kg * 8];
        oacc[0][dt] = mfma16(pa0, vb, oacc[0][dt]);
        oacc[1][dt] = mfma16(pa1, vb, oacc[1][dt]);
      }
    }
  }

#pragma unroll
  for (int mt = 0; mt < 2; ++mt)
#pragma unroll
    for (int dt = 0; dt < 4; ++dt)
#pragma unroll
      for (int rr = 0; rr < 4; ++rr) {
        int t = qrow0 + mt * 16 + kg * 4 + rr;
        obuf[((size_t)b * 128 + t) * 768 + hoff + dt * 16 + lr] = (bf16_t)oacc[mt][dt][rr];
      }
}

// ---------------- launch ----------------
extern "C" void kernel_launch(void* const* d_in, const int* in_sizes, int n_in,
                              void* d_out, int out_size, void* d_ws, size_t ws_size,
                              hipStream_t stream) {
  const float* x = (const float*)d_in[0];       // [128,128,768]
  const float* w_qkv = (const float*)d_in[1];   // [768,2304]
  const float* w_proj = (const float*)d_in[2];  // [768,768]
  float* out = (float*)d_out;
  char* ws = (char*)d_ws;

  bf16_t* xb     = (bf16_t*)(ws);              // 16384*768*2   = 25,165,824
  bf16_t* wqkvt  = (bf16_t*)(ws + 25165824);   // packed 2304*768*2 = 3,538,944
  bf16_t* wprojt = (bf16_t*)(ws + 28704768);   // packed 768*768*2  = 1,179,648
  bf16_t* qkv    = (bf16_t*)(ws + 29884416);   // 16384*2304*2  = 75,497,472
  bf16_t* obuf   = (bf16_t*)(ws + 105381888);  // 16384*768*2   = 25,165,824

  // 12288 convert blocks + (3456+1152)/4 = 1152 weight-pack blocks
  prep_kernel<<<dim3(13440), dim3(256), 0, stream>>>(x, w_qkv, w_proj, xb, wqkvt, wprojt);
  // GEMM1: jobs = 128 bm x 18 bn = 2304 = 768 blocks x 3 (same bm per block)
  gemm_pk<18, 3, false><<<dim3(768), dim3(256), 0, stream>>>(xb, wqkvt, (void*)qkv, 2304);
  attn_kernel<<<dim3(1536), dim3(256), 0, stream>>>(qkv, obuf);
  // GEMM2: jobs = 128 bm x 6 bn = 768 blocks x 1; 3 blocks/CU = 1 round
  gemm_pk<6, 1, true><<<dim3(768), dim3(256), 0, stream>>>(obuf, wprojt, (void*)out, 768);
}